// Round 9
// baseline (414.881 us; speedup 1.0000x reference)
//
// SlotAttention fused forward for MI355X (gfx950) — round 9.
// r9 = r8 with phase A switched to the 16-row/wave design (r4's, proven correct
// in hindsight: r4/r5 failed with identical absmax from the phaseB arena bug
// alone). Tile 128x18 dwords/wave -> 37KB LDS/block -> 3 blocks/CU at
// __launch_bounds__(256,3) (12 waves/CU vs 8), NBLK=64. Softmax C-fragment is
// directly the P-MFMA A-fragment (identity row map); P-step uses
// mfma_f32_16x16x16bf16_1k (or zero-padded 16x16x32 fallback). fusedB reductions
// updated for NBLK=64; fusedB body / k0 / prep unchanged (r7/r8-proven).
#include <hip/hip_runtime.h>
#include <cstdint>
#include <cstddef>

#define BB    16
#define NTOK  16384
#define KS    16
#define DD    256
#define FEATN 256
#define NBLK  64
#define LN_EPS 1e-5f

typedef float        float4v __attribute__((ext_vector_type(4)));
typedef unsigned int uint4v  __attribute__((ext_vector_type(4)));
typedef unsigned int uint2v  __attribute__((ext_vector_type(2)));
typedef __bf16       bf16x8  __attribute__((ext_vector_type(8)));
typedef short        short4v __attribute__((ext_vector_type(4)));

__device__ __forceinline__ float bflo(unsigned u){ return __builtin_bit_cast(float, u << 16); }
__device__ __forceinline__ float bfhi(unsigned u){ return __builtin_bit_cast(float, u & 0xffff0000u); }
__device__ __forceinline__ unsigned short f2bf(float v){ __bf16 b = (__bf16)v; return __builtin_bit_cast(unsigned short, b); }
__device__ __forceinline__ float sigm(float x){ return 1.f/(1.f + __expf(-x)); }

// ---------------------------------------------------------------- weight prep
__global__ void prep_w_kernel(const float* __restrict__ Wv, const float* __restrict__ w_ih,
                              const float* __restrict__ w_hh, const float* __restrict__ W1,
                              const float* __restrict__ W2, const float* __restrict__ Wq,
                              const float* __restrict__ Wk,
                              unsigned short* __restrict__ Wv_t, unsigned short* __restrict__ wih_t,
                              unsigned short* __restrict__ whh_t, unsigned short* __restrict__ W1_t,
                              unsigned short* __restrict__ W2_t, unsigned short* __restrict__ Wq_t,
                              unsigned short* __restrict__ Wk_b)
{
  __shared__ float tile[64][65];
  const int t = blockIdx.x, tid = threadIdx.x;
  const float* src; unsigned short* dst; int R, C, base;
  if      (t < 16)  { src = Wv;   dst = Wv_t;  R = 256;  C = 256;  base = 0;   }
  else if (t < 64)  { src = w_ih; dst = wih_t; R = 768;  C = 256;  base = 16;  }
  else if (t < 112) { src = w_hh; dst = whh_t; R = 768;  C = 256;  base = 64;  }
  else if (t < 176) { src = W1;   dst = W1_t;  R = 1024; C = 256;  base = 112; }
  else if (t < 240) { src = W2;   dst = W2_t;  R = 256;  C = 1024; base = 176; }
  else if (t < 256) { src = Wq;   dst = Wq_t;  R = 256;  C = 256;  base = 240; }
  else {
    const int t2 = t - 256;
    for (int i = tid; i < 4096; i += 256) {
      const int idx = t2*4096 + i;
      Wk_b[idx] = f2bf(Wk[idx]);
    }
    return;
  }
  const int tt = t - base;
  const int tiles_r = R >> 6;
  const int r0 = (tt % tiles_r) * 64, c0 = (tt / tiles_r) * 64;
  const int j = tid & 63, i0 = (tid >> 6) * 16;
  for (int s = 0; s < 16; ++s)
    tile[i0 + s][j] = src[(size_t)(r0 + i0 + s)*C + c0 + j];
  __syncthreads();
  for (int s = 0; s < 16; ++s) {
    const int i = i0 + s;
    dst[(size_t)(c0 + i)*R + r0 + j] = f2bf(tile[j][i]);
  }
}

// ---------------------------------------------------------------- LN->q->u/su/cb tail (k0 only)
__device__ __forceinline__ void lnqu_tail_p(
    const float* Vs, float* Ys, float* Qs, float* Pp, float* SUb, float* CBb,
    const float* __restrict__ g_s, const float* __restrict__ b_s,
    const unsigned short* __restrict__ Wq_t, const unsigned short* __restrict__ Wk_b,
    const float* __restrict__ g_f, const float* __restrict__ b_f,
    unsigned short* __restrict__ u_buf, float* __restrict__ su_buf, float* __restrict__ cb_buf,
    int b, int k0, int tid)
{
  const int w = tid >> 6, L = tid & 63;
  {
    const float v0 = Vs[w*256+L], v1 = Vs[w*256+64+L], v2 = Vs[w*256+128+L], v3 = Vs[w*256+192+L];
    float s = v0+v1+v2+v3;
    #pragma unroll
    for (int m = 1; m < 64; m <<= 1) s += __shfl_xor(s, m);
    const float mean = s * (1.f/DD);
    const float d0 = v0-mean, d1 = v1-mean, d2 = v2-mean, d3 = v3-mean;
    float s2 = d0*d0 + d1*d1 + d2*d2 + d3*d3;
    #pragma unroll
    for (int m = 1; m < 64; m <<= 1) s2 += __shfl_xor(s2, m);
    const float rs = rsqrtf(s2 * (1.f/DD) + LN_EPS);
    Ys[L*4+w]       = d0*rs*g_s[L]      + b_s[L];
    Ys[(64+L)*4+w]  = d1*rs*g_s[64+L]   + b_s[64+L];
    Ys[(128+L)*4+w] = d2*rs*g_s[128+L]  + b_s[128+L];
    Ys[(192+L)*4+w] = d3*rs*g_s[192+L]  + b_s[192+L];
  }
  __syncthreads();
  {
    float acc[4][4] = {};
    for (int cc = w*64; cc < w*64+64; ++cc) {
      const float4v xv = *reinterpret_cast<const float4v*>(Ys + cc*4);
      const uint2v wr = *reinterpret_cast<const uint2v*>(Wq_t + (size_t)cc*DD + 4*L);
      const float w0 = bflo(wr[0]), w1 = bfhi(wr[0]), w2 = bflo(wr[1]), w3 = bfhi(wr[1]);
      #pragma unroll
      for (int s = 0; s < 4; ++s) {
        acc[s][0] += xv[s]*w0; acc[s][1] += xv[s]*w1;
        acc[s][2] += xv[s]*w2; acc[s][3] += xv[s]*w3;
      }
    }
    #pragma unroll
    for (int s = 0; s < 4; ++s)
      *reinterpret_cast<float4v*>(Pp + (w*4+s)*256 + 4*L) = *reinterpret_cast<const float4v*>(acc[s]);
  }
  __syncthreads();
  for (int i = tid; i < 4*DD; i += 256) {
    const int kk = i >> 8, d = i & 255;
    Qs[d*4+kk] = Pp[(0*4+kk)*256+d] + Pp[(1*4+kk)*256+d] + Pp[(2*4+kk)*256+d] + Pp[(3*4+kk)*256+d];
  }
  __syncthreads();
  {
    float acc[4][4] = {};
    for (int d = w*64; d < w*64+64; ++d) {
      const float4v xv = *reinterpret_cast<const float4v*>(Qs + d*4);
      const uint2v wr = *reinterpret_cast<const uint2v*>(Wk_b + (size_t)d*DD + 4*L);
      const float w0 = bflo(wr[0]), w1 = bfhi(wr[0]), w2 = bflo(wr[1]), w3 = bfhi(wr[1]);
      #pragma unroll
      for (int s = 0; s < 4; ++s) {
        acc[s][0] += xv[s]*w0; acc[s][1] += xv[s]*w1;
        acc[s][2] += xv[s]*w2; acc[s][3] += xv[s]*w3;
      }
    }
    #pragma unroll
    for (int s = 0; s < 4; ++s)
      *reinterpret_cast<float4v*>(Pp + (w*4+s)*256 + 4*L) = *reinterpret_cast<const float4v*>(acc[s]);
  }
  __syncthreads();
  for (int i = tid; i < 4*DD; i += 256) {
    const int kk = i >> 8, cc = i & 255;
    const float qk = Pp[(0*4+kk)*256+cc] + Pp[(1*4+kk)*256+cc] + Pp[(2*4+kk)*256+cc] + Pp[(3*4+kk)*256+cc];
    const float uv = qk * g_f[cc];
    u_buf[(size_t)(b*KS + k0 + kk)*DD + cc] = f2bf(uv);
    SUb[kk*256+cc] = uv;
    CBb[kk*256+cc] = qk * b_f[cc];
  }
  __syncthreads();
  {
    float s  = SUb[w*256+L] + SUb[w*256+64+L] + SUb[w*256+128+L] + SUb[w*256+192+L];
    float cv = CBb[w*256+L] + CBb[w*256+64+L] + CBb[w*256+128+L] + CBb[w*256+192+L];
    #pragma unroll
    for (int m = 1; m < 64; m <<= 1) { s += __shfl_xor(s, m); cv += __shfl_xor(cv, m); }
    if (L == 0) { su_buf[b*KS + k0 + w] = s; cb_buf[b*KS + k0 + w] = cv; }
  }
}

// ---------------------------------------------------------------- K0 (initial u only)
__global__ void k0_kernel(const float* __restrict__ slots_init,
                          const float* __restrict__ g_s, const float* __restrict__ b_s,
                          const unsigned short* __restrict__ Wq_t, const unsigned short* __restrict__ Wk_b,
                          const float* __restrict__ g_f, const float* __restrict__ b_f,
                          unsigned short* __restrict__ u_buf, float* __restrict__ su_buf,
                          float* __restrict__ cb_buf)
{
  const int b = blockIdx.x >> 2, k0 = (blockIdx.x & 3) * 4;
  const int tid = threadIdx.x;
  __shared__ __align__(16) float Vs[4*DD];
  __shared__ __align__(16) float Ys[DD*4];
  __shared__ __align__(16) float Qs[DD*4];
  __shared__ __align__(16) float Pp[4*4*DD];
  __shared__ __align__(16) float SUb[4*DD];
  __shared__ __align__(16) float CBb[4*DD];
  for (int i = tid; i < 4*DD; i += 256)
    Vs[i] = slots_init[(size_t)(b*KS + k0)*DD + i];
  __syncthreads();
  lnqu_tail_p(Vs, Ys, Qs, Pp, SUb, CBb, g_s, b_s, Wq_t, Wk_b, g_f, b_f,
              u_buf, su_buf, cb_buf, b, k0, tid);
}

// ---------------------------------------------------------------- phase A: 16 rows/wave/pass
// Tile per wave: [128 d-pairs][18] dwords (16 token cols + 2 pad). 37KB/block.
template<int MODE, int LAST>
__launch_bounds__(256, (MODE==0) ? 2 : 3)
__global__ void phaseA_kernel(const float* __restrict__ feat,
                              unsigned short* __restrict__ xb, float* __restrict__ stats,
                              const unsigned short* __restrict__ u_buf,
                              const float* __restrict__ su_buf,
                              const float* __restrict__ cb_buf,
                              float* __restrict__ P_part,
                              float* __restrict__ S_part,
                              float* __restrict__ R_part,
                              float* __restrict__ attn_out)
{
  __shared__ __align__(16) unsigned int xl[4][128*18];
  __shared__ float ssh[4][16];
  __shared__ float rsh[4][16];

  const int b   = blockIdx.x / NBLK;
  const int blk = blockIdx.x - b*NBLK;
  const int tid = threadIdx.x;
  const int w = tid >> 6;
  const int l = tid & 63;
  const int c = l & 15;
  const int g = l >> 4;

  bf16x8 ufrag[8];
  {
    const bf16x8* up = reinterpret_cast<const bf16x8*>(u_buf + (size_t)(b*KS + c)*DD);
    #pragma unroll
    for (int kk = 0; kk < 8; ++kk) ufrag[kk] = up[4*kk + g];
  }
  const float su_c = su_buf[b*KS + c];
  const float cb_c = cb_buf[b*KS + c];

  float4v Pacc[16];
  #pragma unroll
  for (int t = 0; t < 16; ++t) Pacc[t] = (float4v){0.f,0.f,0.f,0.f};
  float S_acc = 0.f, R_acc = 0.f;
  unsigned int* myxl = xl[w];

  for (int pass = 0; pass < 4; ++pass) {
    const int n0 = blk*(NTOK/NBLK) + pass*64 + w*16;
    const size_t row = (size_t)b*NTOK + (size_t)(n0 + c);
    float4v Cacc = (float4v){0.f,0.f,0.f,0.f};
    float m_c, rs_c;

    if constexpr (MODE == 0) {
      const float* fr = feat + row*FEATN;
      unsigned short* xw = xb + row*FEATN;
      float4v xf[16];
      #pragma unroll
      for (int kk = 0; kk < 8; ++kk) {
        xf[2*kk]   = *reinterpret_cast<const float4v*>(fr + 32*kk + 8*g);
        xf[2*kk+1] = *reinterpret_cast<const float4v*>(fr + 32*kk + 8*g + 4);
      }
      float sum = 0.f, sq = 0.f;
      #pragma unroll
      for (int kk = 0; kk < 8; ++kk) {
        const float4v x0 = xf[2*kk], x1 = xf[2*kk+1];
        sum += x0[0]+x0[1]+x0[2]+x0[3] + x1[0]+x1[1]+x1[2]+x1[3];
        sq  += x0[0]*x0[0]+x0[1]*x0[1]+x0[2]*x0[2]+x0[3]*x0[3]
             + x1[0]*x1[0]+x1[1]*x1[1]+x1[2]*x1[2]+x1[3]*x1[3];
        bf16x8 af;
        af[0]=(__bf16)x0[0]; af[1]=(__bf16)x0[1]; af[2]=(__bf16)x0[2]; af[3]=(__bf16)x0[3];
        af[4]=(__bf16)x1[0]; af[5]=(__bf16)x1[1]; af[6]=(__bf16)x1[2]; af[7]=(__bf16)x1[3];
        *reinterpret_cast<bf16x8*>(xw + 32*kk + 8*g) = af;
        const uint4v ad = __builtin_bit_cast(uint4v, af);
        const int pb = (16*kk + 4*g)*18 + c;
        myxl[pb     ] = ad[0];
        myxl[pb + 18] = ad[1];
        myxl[pb + 36] = ad[2];
        myxl[pb + 54] = ad[3];
        Cacc = __builtin_amdgcn_mfma_f32_16x16x32_bf16(af, ufrag[kk], Cacc, 0, 0, 0);
      }
      sum += __shfl_xor(sum,16); sum += __shfl_xor(sum,32);
      sq  += __shfl_xor(sq ,16); sq  += __shfl_xor(sq ,32);
      m_c = sum * (1.f/FEATN);
      const float var = sq * (1.f/FEATN) - m_c*m_c;
      rs_c = rsqrtf(var + LN_EPS);
      if (g == 0) {
        float2 st; st.x = m_c; st.y = rs_c;
        *reinterpret_cast<float2*>(stats + row*2) = st;
      }
    } else {
      const unsigned short* xr0p = xb + row*FEATN;
      bf16x8 xr[8];
      {
        const bf16x8* pv = reinterpret_cast<const bf16x8*>(xr0p);
        #pragma unroll
        for (int kk = 0; kk < 8; ++kk) xr[kk] = pv[4*kk + g];
      }
      const float2 st = *reinterpret_cast<const float2*>(stats + row*2);
      m_c = st.x; rs_c = st.y;
      #pragma unroll
      for (int kk = 0; kk < 8; ++kk) {
        const bf16x8 af = xr[kk];
        const uint4v ad = __builtin_bit_cast(uint4v, af);
        const int pb = (16*kk + 4*g)*18 + c;
        myxl[pb     ] = ad[0];
        myxl[pb + 18] = ad[1];
        myxl[pb + 36] = ad[2];
        myxl[pb + 54] = ad[3];
        Cacc = __builtin_amdgcn_mfma_f32_16x16x32_bf16(af, ufrag[kk], Cacc, 0, 0, 0);
      }
    }

    // softmax over slots; lane (c,g) reg r holds logits[row n0+4g+r][slot c]
    float arr[4], a_[4];
    #pragma unroll
    for (int r = 0; r < 4; ++r) {
      const int src = 4*g + r;
      const float rsr = __shfl(rs_c, src);
      const float mrr = __shfl(m_c,  src);
      const float lv = 0.0625f * (rsr*(Cacc[r] - mrr*su_c) + cb_c);
      float v = lv;
      v = fmaxf(v, __shfl_xor(v,1));
      v = fmaxf(v, __shfl_xor(v,2));
      v = fmaxf(v, __shfl_xor(v,4));
      v = fmaxf(v, __shfl_xor(v,8));
      const float e = __expf(lv - v);
      float s = e;
      s += __shfl_xor(s,1);
      s += __shfl_xor(s,2);
      s += __shfl_xor(s,4);
      s += __shfl_xor(s,8);
      const float a = e / s;
      a_[r] = a;
      S_acc += a;
      R_acc += a * rsr * mrr;
      arr[r] = a * rsr;
    }
    if (LAST) {
      float4v av = {a_[0], a_[1], a_[2], a_[3]};
      *reinterpret_cast<float4v*>(attn_out + (size_t)(b*KS + c)*NTOK + (size_t)(n0 + 4*g)) = av;
    }

#if __has_builtin(__builtin_amdgcn_mfma_f32_16x16x16bf16_1k)
    short4v afrag;
    afrag[0] = (short)f2bf(arr[0]); afrag[1] = (short)f2bf(arr[1]);
    afrag[2] = (short)f2bf(arr[2]); afrag[3] = (short)f2bf(arr[3]);
    const unsigned int sel = (c & 1) ? 0x07060302u : 0x05040100u;
    #pragma unroll
    for (int t = 0; t < 16; ++t) {
      const unsigned int* rp = &myxl[(t*8 + (c>>1))*18 + 4*g];
      const uint2v d0 = *reinterpret_cast<const uint2v*>(rp);
      const uint2v d1 = *reinterpret_cast<const uint2v*>(rp + 2);
      uint2v bd;
      bd[0] = __builtin_amdgcn_perm(d0[1], d0[0], sel);
      bd[1] = __builtin_amdgcn_perm(d1[1], d1[0], sel);
      const short4v bfrag = __builtin_bit_cast(short4v, bd);
      Pacc[t] = __builtin_amdgcn_mfma_f32_16x16x16bf16_1k(afrag, bfrag, Pacc[t], 0, 0, 0);
    }
#else
    // fallback: zero-padded 16x16x32 (token rows 16..31 zero)
    bf16x8 afrag8;
    #pragma unroll
    for (int j = 0; j < 8; ++j) {
      const int srcl = c + 16*(2*g + (j>>2));
      const float v = __shfl(arr[j & 3], srcl);
      afrag8[j] = (g < 2) ? (__bf16)v : (__bf16)0.f;
    }
    const unsigned int sel = (c & 1) ? 0x07060302u : 0x05040100u;
    #pragma unroll
    for (int t = 0; t < 16; ++t) {
      uint4v bd = (uint4v){0u,0u,0u,0u};
      if (g < 2) {
        const unsigned int* rp = &myxl[(t*8 + (c>>1))*18 + 8*g];
        const uint2v d0 = *reinterpret_cast<const uint2v*>(rp);
        const uint2v d1 = *reinterpret_cast<const uint2v*>(rp + 2);
        const uint2v d2 = *reinterpret_cast<const uint2v*>(rp + 4);
        const uint2v d3 = *reinterpret_cast<const uint2v*>(rp + 6);
        bd[0] = __builtin_amdgcn_perm(d0[1], d0[0], sel);
        bd[1] = __builtin_amdgcn_perm(d1[1], d1[0], sel);
        bd[2] = __builtin_amdgcn_perm(d2[1], d2[0], sel);
        bd[3] = __builtin_amdgcn_perm(d3[1], d3[0], sel);
      }
      const bf16x8 bfrag = __builtin_bit_cast(bf16x8, bd);
      Pacc[t] = __builtin_amdgcn_mfma_f32_16x16x32_bf16(afrag8, bfrag, Pacc[t], 0, 0, 0);
    }
#endif
  }

  S_acc += __shfl_xor(S_acc,16); S_acc += __shfl_xor(S_acc,32);
  R_acc += __shfl_xor(R_acc,16); R_acc += __shfl_xor(R_acc,32);
  if (g == 0) { ssh[w][c] = S_acc; rsh[w][c] = R_acc; }

  // P dump + block combine, two halves (2048 floats per half; tile holds 2304)
  float* pf = reinterpret_cast<float*>(&xl[w][0]);
  #pragma unroll
  for (int half = 0; half < 2; ++half) {
    __syncthreads();
    #pragma unroll
    for (int t = 0; t < 8; ++t) {
      #pragma unroll
      for (int r = 0; r < 4; ++r)
        pf[(4*g + r)*128 + t*16 + c] = Pacc[half*8 + t][r];
    }
    __syncthreads();
    float* outp = P_part + (size_t)blockIdx.x * (KS*DD) + half*128;
    const float* p0 = reinterpret_cast<const float*>(&xl[0][0]);
    const float* p1 = p0 + 2304;
    const float* p2 = p0 + 4608;
    const float* p3 = p0 + 6912;
    for (int i = tid; i < 2048; i += 256) {
      const int rowk = i >> 7, rem = i & 127;
      outp[rowk*256 + rem] = p0[i] + p1[i] + p2[i] + p3[i];
    }
  }
  if (tid < KS) {
    S_part[blockIdx.x*KS + tid] = ssh[0][tid]+ssh[1][tid]+ssh[2][tid]+ssh[3][tid];
    R_part[blockIdx.x*KS + tid] = rsh[0][tid]+rsh[1][tid]+rsh[2][tid]+rsh[3][tid];
  }
}

// ---------------------------------------------------------------- fused slot update + next-iter tail
// grid = BB*KS = 256 blocks, 256 threads, one slot each. Arena non-overlapping.
template<int LAST, int NEXT>
__global__ void fusedB_kernel(const float* __restrict__ P_part, const float* __restrict__ S_part,
                              const float* __restrict__ R_part, const float* __restrict__ slots_in,
                              const float* __restrict__ g_f, const float* __restrict__ b_f,
                              const unsigned short* __restrict__ Wv_t,
                              const unsigned short* __restrict__ wih_t,
                              const unsigned short* __restrict__ whh_t,
                              const float* __restrict__ b_ih, const float* __restrict__ b_hh,
                              const float* __restrict__ g_m, const float* __restrict__ b_m,
                              const unsigned short* __restrict__ W1_t, const float* __restrict__ b1,
                              const unsigned short* __restrict__ W2_t, const float* __restrict__ b2v,
                              const float* __restrict__ g_s, const float* __restrict__ b_s,
                              const unsigned short* __restrict__ Wq_t,
                              const unsigned short* __restrict__ Wk_b,
                              float* __restrict__ slots_next, float* __restrict__ out_slots,
                              unsigned short* __restrict__ u_buf, float* __restrict__ su_buf,
                              float* __restrict__ cb_buf)
{
  const int b = blockIdx.x >> 4, k = blockIdx.x & 15;
  const int tid = threadIdx.x;
  const int w = tid >> 6, L = tid & 63;

  __shared__ __align__(16) float arena[9984];
  __shared__ float SRsh[2];
  __shared__ float redsh[8];

  float* Pp    = arena;
  float* Hsh   = arena + 6144;
  float* Tsh   = arena + 6400;
  float* Ush   = arena + 6656;
  float* Gish  = arena + 6912;
  float* Ghsh  = arena + 7680;
  float* Hpsh  = arena + 8448;
  float* Ysh   = arena + 8704;
  float* Hidsh = arena + 8960;

  // ---- slots_in load + S/R reduce (NBLK=64 partials)
  Hsh[tid] = slots_in[(size_t)(b*KS + k)*DD + tid];
  if (tid < 128) {
    const int which = tid >> 6;           // 0: S, 1: R
    const int p = tid & 63;
    const float* sp = which ? R_part : S_part;
    float v = sp[(b*NBLK + p)*KS + k];
    #pragma unroll
    for (int m = 1; m < 64; m <<= 1) v += __shfl_xor(v, m);
    if (p == 0) SRsh[which] = v;
  }
  __syncthreads();

  // ---- T[d] = (g_f*(P - R) + S*b_f)/(S+1)
  {
    const float S = SRsh[0], R = SRsh[1];
    const float inv = 1.f / (S + 1.f);
    const float* pb = P_part + (size_t)(b*NBLK)*KS*DD + (size_t)k*DD + tid;
    float p0 = 0.f, p1 = 0.f, p2 = 0.f, p3 = 0.f;
    #pragma unroll 4
    for (int p = 0; p < NBLK; p += 4) {
      p0 += pb[(size_t)(p+0)*KS*DD];
      p1 += pb[(size_t)(p+1)*KS*DD];
      p2 += pb[(size_t)(p+2)*KS*DD];
      p3 += pb[(size_t)(p+3)*KS*DD];
    }
    const float P = (p0 + p1) + (p2 + p3);
    Tsh[tid] = (g_f[tid]*(P - R) + S*b_f[tid]) * inv;
  }
  __syncthreads();

  // ---- upd = T @ Wv^T
  {
    const int c0 = 4*L;
    float a0 = 0.f, a1 = 0.f, a2 = 0.f, a3 = 0.f;
    for (int cc = w*64; cc < w*64+64; ++cc) {
      const float x = Tsh[cc];
      const uint2v wr = *reinterpret_cast<const uint2v*>(Wv_t + (size_t)cc*DD + c0);
      a0 += x*bflo(wr[0]); a1 += x*bfhi(wr[0]);
      a2 += x*bflo(wr[1]); a3 += x*bfhi(wr[1]);
    }
    float4v av = {a0, a1, a2, a3};
    *reinterpret_cast<float4v*>(Pp + w*256 + c0) = av;
  }
  __syncthreads();
  Ush[tid] = Pp[tid] + Pp[256+tid] + Pp[512+tid] + Pp[768+tid];
  __syncthreads();

  // ---- gi = upd@w_ih^T, gh = slots@w_hh^T
  {
    const int c0 = 4*L;
    float ai[3][4] = {}, ah[3][4] = {};
    for (int cc = w*64; cc < w*64+64; ++cc) {
      const float xi = Ush[cc], xh = Hsh[cc];
      #pragma unroll
      for (int c = 0; c < 3; ++c) {
        const uint2v wi = *reinterpret_cast<const uint2v*>(wih_t + (size_t)cc*768 + c0 + 256*c);
        const uint2v wh = *reinterpret_cast<const uint2v*>(whh_t + (size_t)cc*768 + c0 + 256*c);
        ai[c][0] += xi*bflo(wi[0]); ai[c][1] += xi*bfhi(wi[0]);
        ai[c][2] += xi*bflo(wi[1]); ai[c][3] += xi*bfhi(wi[1]);
        ah[c][0] += xh*bflo(wh[0]); ah[c][1] += xh*bfhi(wh[0]);
        ah[c][2] += xh*bflo(wh[1]); ah[c][3] += xh*bfhi(wh[1]);
      }
    }
    #pragma unroll
    for (int c = 0; c < 3; ++c) {
      *reinterpret_cast<float4v*>(Pp + w*768 + 256*c + c0)        = *reinterpret_cast<const float4v*>(ai[c]);
      *reinterpret_cast<float4v*>(Pp + 3072 + w*768 + 256*c + c0) = *reinterpret_cast<const float4v*>(ah[c]);
    }
  }
  __syncthreads();
  for (int j = tid; j < 768; j += 256) {
    Gish[j] = b_ih[j] + Pp[j] + Pp[768+j] + Pp[1536+j] + Pp[2304+j];
    Ghsh[j] = b_hh[j] + Pp[3072+j] + Pp[3840+j] + Pp[4608+j] + Pp[5376+j];
  }
  __syncthreads();

  // ---- GRU combine + LN(g_m,b_m)
  {
    const int d = tid;
    const float r = sigm(Gish[d] + Ghsh[d]);
    const float z = sigm(Gish[256+d] + Ghsh[256+d]);
    const float n = tanhf(Gish[512+d] + r*Ghsh[512+d]);
    const float hp = (1.f - z)*n + z*Hsh[d];
    Hpsh[d] = hp;
    float s = hp;
    #pragma unroll
    for (int m = 1; m < 64; m <<= 1) s += __shfl_xor(s, m);
    if (L == 0) redsh[w] = s;
    __syncthreads();
    const float mean = (redsh[0]+redsh[1]+redsh[2]+redsh[3]) * (1.f/DD);
    const float dv = hp - mean;
    float s2 = dv*dv;
    #pragma unroll
    for (int m = 1; m < 64; m <<= 1) s2 += __shfl_xor(s2, m);
    if (L == 0) redsh[4+w] = s2;
    __syncthreads();
    const float var = (redsh[4]+redsh[5]+redsh[6]+redsh[7]) * (1.f/DD);
    Ysh[d] = dv * rsqrtf(var + LN_EPS) * g_m[d] + b_m[d];
  }
  __syncthreads();

  // ---- MLP1
  {
    const int c0 = 4*L;
    float a[4][4] = {};
    for (int cc = w*64; cc < w*64+64; ++cc) {
      const float x = Ysh[cc];
      #pragma unroll
      for (int c = 0; c < 4; ++c) {
        const uint2v wr = *reinterpret_cast<const uint2v*>(W1_t + (size_t)cc*1024 + c0 + 256*c);
        a[c][0] += x*bflo(wr[0]); a[c][1] += x*bfhi(wr[0]);
        a[c][2] += x*bflo(wr[1]); a[c][3] += x*bfhi(wr[1]);
      }
    }
    #pragma unroll
    for (int c = 0; c < 4; ++c)
      *reinterpret_cast<float4v*>(Pp + w*1024 + 256*c + c0) = *reinterpret_cast<const float4v*>(a[c]);
  }
  __syncthreads();
  for (int j = tid; j < 1024; j += 256)
    Hidsh[j] = fmaxf(b1[j] + Pp[j] + Pp[1024+j] + Pp[2048+j] + Pp[3072+j], 0.f);
  __syncthreads();

  // ---- MLP2 + residual
  {
    const int c0 = 4*L;
    float a0 = 0.f, a1 = 0.f, a2 = 0.f, a3 = 0.f;
    for (int cc = w*256; cc < w*256+256; ++cc) {
      const float x = Hidsh[cc];
      const uint2v wr = *reinterpret_cast<const uint2v*>(W2_t + (size_t)cc*DD + c0);
      a0 += x*bflo(wr[0]); a1 += x*bfhi(wr[0]);
      a2 += x*bflo(wr[1]); a3 += x*bfhi(wr[1]);
    }
    float4v av = {a0, a1, a2, a3};
    *reinterpret_cast<float4v*>(Pp + w*256 + c0) = av;
  }
  __syncthreads();
  {
    const int d = tid;
    const float v = b2v[d] + Pp[d] + Pp[256+d] + Pp[512+d] + Pp[768+d] + Hpsh[d];
    Tsh[d] = v;
    slots_next[(size_t)(b*KS + k)*DD + d] = v;
    if (LAST) out_slots[(size_t)(b*KS + k)*DD + d] = v;
  }

  // ---- next-iteration LN(g_s,b_s) -> q -> u/su/cb
  if constexpr (NEXT) {
    __syncthreads();
    {
      const float v = Tsh[tid];
      float s = v;
      #pragma unroll
      for (int m = 1; m < 64; m <<= 1) s += __shfl_xor(s, m);
      if (L == 0) redsh[w] = s;
      __syncthreads();
      const float mean = (redsh[0]+redsh[1]+redsh[2]+redsh[3]) * (1.f/DD);
      const float dv = v - mean;
      float s2 = dv*dv;
      #pragma unroll
      for (int m = 1; m < 64; m <<= 1) s2 += __shfl_xor(s2, m);
      if (L == 0) redsh[4+w] = s2;
      __syncthreads();
      const float var = (redsh[4]+redsh[5]+redsh[6]+redsh[7]) * (1.f/DD);
      Ush[tid] = dv * rsqrtf(var + LN_EPS) * g_s[tid] + b_s[tid];
    }
    __syncthreads();
    {
      const int c0 = 4*L;
      float a0 = 0.f, a1 = 0.f, a2 = 0.f, a3 = 0.f;
      for (int cc = w*64; cc < w*64+64; ++cc) {
        const float x = Ush[cc];
        const uint2v wr = *reinterpret_cast<const uint2v*>(Wq_t + (size_t)cc*DD + c0);
        a0 += x*bflo(wr[0]); a1 += x*bfhi(wr[0]);
        a2 += x*bflo(wr[1]); a3 += x*bfhi(wr[1]);
      }
      float4v av = {a0, a1, a2, a3};
      *reinterpret_cast<float4v*>(Pp + w*256 + c0) = av;
    }
    __syncthreads();
    Hsh[tid] = Pp[tid] + Pp[256+tid] + Pp[512+tid] + Pp[768+tid];
    __syncthreads();
    {
      const int c0 = 4*L;
      float a0 = 0.f, a1 = 0.f, a2 = 0.f, a3 = 0.f;
      for (int dd = w*64; dd < w*64+64; ++dd) {
        const float x = Hsh[dd];
        const uint2v wr = *reinterpret_cast<const uint2v*>(Wk_b + (size_t)dd*DD + c0);
        a0 += x*bflo(wr[0]); a1 += x*bfhi(wr[0]);
        a2 += x*bflo(wr[1]); a3 += x*bfhi(wr[1]);
      }
      float4v av = {a0, a1, a2, a3};
      *reinterpret_cast<float4v*>(Pp + w*256 + c0) = av;
    }
    __syncthreads();
    {
      const int cidx = tid;
      const float qk = Pp[cidx] + Pp[256+cidx] + Pp[512+cidx] + Pp[768+cidx];
      const float uv = qk * g_f[cidx];
      u_buf[(size_t)(b*KS + k)*DD + cidx] = f2bf(uv);
      float s  = uv;
      float cv = qk * b_f[cidx];
      #pragma unroll
      for (int m = 1; m < 64; m <<= 1) { s += __shfl_xor(s, m); cv += __shfl_xor(cv, m); }
      if (L == 0) { redsh[w] = s; redsh[4+w] = cv; }
      __syncthreads();
      if (tid == 0) {
        su_buf[b*KS + k] = redsh[0]+redsh[1]+redsh[2]+redsh[3];
        cb_buf[b*KS + k] = redsh[4]+redsh[5]+redsh[6]+redsh[7];
      }
    }
  }
}

// ---------------------------------------------------------------- host
extern "C" void kernel_launch(void* const* d_in, const int* in_sizes, int n_in,
                              void* d_out, int out_size, void* d_ws, size_t ws_size,
                              hipStream_t stream)
{
  const float* features   = (const float*)d_in[0];
  const float* slots_init = (const float*)d_in[1];
  const float* g_f = (const float*)d_in[2];
  const float* b_f = (const float*)d_in[3];
  const float* g_s = (const float*)d_in[4];
  const float* b_s = (const float*)d_in[5];
  const float* g_m = (const float*)d_in[6];
  const float* b_m = (const float*)d_in[7];
  const float* Wq  = (const float*)d_in[8];
  const float* Wk  = (const float*)d_in[9];
  const float* Wv  = (const float*)d_in[10];
  const float* w_ih = (const float*)d_in[11];
  const float* w_hh = (const float*)d_in[12];
  const float* b_ih = (const float*)d_in[13];
  const float* b_hh = (const float*)d_in[14];
  const float* W1  = (const float*)d_in[15];
  const float* b1  = (const float*)d_in[16];
  const float* W2  = (const float*)d_in[17];
  const float* b2  = (const float*)d_in[18];

  float* out_slots = (float*)d_out;
  float* out_attn  = out_slots + (size_t)BB*KS*DD;

  char* ws = (char*)d_ws;
  size_t off = 0;
  auto alloc = [&](size_t bytes) -> void* {
    void* p = ws + off;
    off += (bytes + 255) & ~(size_t)255;
    return p;
  };
  unsigned short* u_buf  = (unsigned short*)alloc((size_t)BB*KS*DD*2);
  float*          su_buf = (float*)alloc((size_t)BB*KS*4);
  float*          cb_buf = (float*)alloc((size_t)BB*KS*4);
  float*          P_part = (float*)alloc((size_t)BB*NBLK*KS*DD*4);
  float*          S_part = (float*)alloc((size_t)BB*NBLK*KS*4);
  float*          R_part = (float*)alloc((size_t)BB*NBLK*KS*4);
  float*          slots_ws = (float*)alloc((size_t)BB*KS*DD*4);
  unsigned short* Wv_t  = (unsigned short*)alloc((size_t)256*256*2);
  unsigned short* wih_t = (unsigned short*)alloc((size_t)256*768*2);
  unsigned short* whh_t = (unsigned short*)alloc((size_t)256*768*2);
  unsigned short* W1_t  = (unsigned short*)alloc((size_t)256*1024*2);
  unsigned short* W2_t  = (unsigned short*)alloc((size_t)1024*256*2);
  unsigned short* Wq_t  = (unsigned short*)alloc((size_t)256*256*2);
  unsigned short* Wk_b  = (unsigned short*)alloc((size_t)256*256*2);
  float*          stats = (float*)alloc((size_t)BB*NTOK*2*4);
  unsigned short* xb    = (unsigned short*)alloc((size_t)BB*NTOK*FEATN*2);
  (void)in_sizes; (void)n_in; (void)out_size; (void)ws_size;

  prep_w_kernel<<<272, 256, 0, stream>>>(Wv, w_ih, w_hh, W1, W2, Wq, Wk,
                                         Wv_t, wih_t, whh_t, W1_t, W2_t, Wq_t, Wk_b);
  k0_kernel<<<BB*4, 256, 0, stream>>>(slots_init, g_s, b_s, Wq_t, Wk_b, g_f, b_f,
                                      u_buf, su_buf, cb_buf);

  // iter 0
  phaseA_kernel<0,0><<<BB*NBLK, 256, 0, stream>>>(features, xb, stats, u_buf, su_buf, cb_buf,
                                                  P_part, S_part, R_part, out_attn);
  fusedB_kernel<0,1><<<BB*KS, 256, 0, stream>>>(P_part, S_part, R_part, slots_init, g_f, b_f,
                                                Wv_t, wih_t, whh_t, b_ih, b_hh, g_m, b_m,
                                                W1_t, b1, W2_t, b2, g_s, b_s, Wq_t, Wk_b,
                                                slots_ws, out_slots, u_buf, su_buf, cb_buf);
  // iter 1
  phaseA_kernel<1,0><<<BB*NBLK, 256, 0, stream>>>(features, xb, stats, u_buf, su_buf, cb_buf,
                                                  P_part, S_part, R_part, out_attn);
  fusedB_kernel<0,1><<<BB*KS, 256, 0, stream>>>(P_part, S_part, R_part, slots_ws, g_f, b_f,
                                                Wv_t, wih_t, whh_t, b_ih, b_hh, g_m, b_m,
                                                W1_t, b1, W2_t, b2, g_s, b_s, Wq_t, Wk_b,
                                                slots_ws, out_slots, u_buf, su_buf, cb_buf);
  // iter 2
  phaseA_kernel<1,1><<<BB*NBLK, 256, 0, stream>>>(features, xb, stats, u_buf, su_buf, cb_buf,
                                                  P_part, S_part, R_part, out_attn);
  fusedB_kernel<1,0><<<BB*KS, 256, 0, stream>>>(P_part, S_part, R_part, slots_ws, g_f, b_f,
                                                Wv_t, wih_t, whh_t, b_ih, b_hh, g_m, b_m,
                                                W1_t, b1, W2_t, b2, g_s, b_s, Wq_t, Wk_b,
                                                slots_ws, out_slots, u_buf, su_buf, cb_buf);
}

// Round 10
// 394.857 us; speedup vs baseline: 1.0507x; 1.0507x over previous
//
// SlotAttention fused forward for MI355X (gfx950) — round 10.
// r10 = r8 (proven 390us baseline: 32-row phaseA, NBLK=32, fusedB+NEXT tail)
// plus two phaseA changes targeting its per-wave serial chain (r9's occupancy
// theory was refuted: 16-row/NBLK=64 regressed to 415):
//  (1) MODE1 software pipeline: double-buffered register prefetch, next pass's
//      16 b128 loads issued before current pass's ds_write/MFMA/softmax/P-step.
//  (2) split QK accumulators (Ca/Cb alternating kk) -> dependent chain 8->4.
#include <hip/hip_runtime.h>
#include <cstdint>
#include <cstddef>

#define BB    16
#define NTOK  16384
#define KS    16
#define DD    256
#define FEATN 256
#define NBLK  32
#define LN_EPS 1e-5f

typedef float        float4v __attribute__((ext_vector_type(4)));
typedef unsigned int uint4v  __attribute__((ext_vector_type(4)));
typedef unsigned int uint2v  __attribute__((ext_vector_type(2)));
typedef __bf16       bf16x8  __attribute__((ext_vector_type(8)));

__device__ __forceinline__ float bflo(unsigned u){ return __builtin_bit_cast(float, u << 16); }
__device__ __forceinline__ float bfhi(unsigned u){ return __builtin_bit_cast(float, u & 0xffff0000u); }
__device__ __forceinline__ unsigned short f2bf(float v){ __bf16 b = (__bf16)v; return __builtin_bit_cast(unsigned short, b); }
__device__ __forceinline__ float sigm(float x){ return 1.f/(1.f + __expf(-x)); }

// ---------------------------------------------------------------- weight prep
__global__ void prep_w_kernel(const float* __restrict__ Wv, const float* __restrict__ w_ih,
                              const float* __restrict__ w_hh, const float* __restrict__ W1,
                              const float* __restrict__ W2, const float* __restrict__ Wq,
                              const float* __restrict__ Wk,
                              unsigned short* __restrict__ Wv_t, unsigned short* __restrict__ wih_t,
                              unsigned short* __restrict__ whh_t, unsigned short* __restrict__ W1_t,
                              unsigned short* __restrict__ W2_t, unsigned short* __restrict__ Wq_t,
                              unsigned short* __restrict__ Wk_b)
{
  __shared__ float tile[64][65];
  const int t = blockIdx.x, tid = threadIdx.x;
  const float* src; unsigned short* dst; int R, C, base;
  if      (t < 16)  { src = Wv;   dst = Wv_t;  R = 256;  C = 256;  base = 0;   }
  else if (t < 64)  { src = w_ih; dst = wih_t; R = 768;  C = 256;  base = 16;  }
  else if (t < 112) { src = w_hh; dst = whh_t; R = 768;  C = 256;  base = 64;  }
  else if (t < 176) { src = W1;   dst = W1_t;  R = 1024; C = 256;  base = 112; }
  else if (t < 240) { src = W2;   dst = W2_t;  R = 256;  C = 1024; base = 176; }
  else if (t < 256) { src = Wq;   dst = Wq_t;  R = 256;  C = 256;  base = 240; }
  else {
    const int t2 = t - 256;
    for (int i = tid; i < 4096; i += 256) {
      const int idx = t2*4096 + i;
      Wk_b[idx] = f2bf(Wk[idx]);
    }
    return;
  }
  const int tt = t - base;
  const int tiles_r = R >> 6;
  const int r0 = (tt % tiles_r) * 64, c0 = (tt / tiles_r) * 64;
  const int j = tid & 63, i0 = (tid >> 6) * 16;
  for (int s = 0; s < 16; ++s)
    tile[i0 + s][j] = src[(size_t)(r0 + i0 + s)*C + c0 + j];
  __syncthreads();
  for (int s = 0; s < 16; ++s) {
    const int i = i0 + s;
    dst[(size_t)(c0 + i)*R + r0 + j] = f2bf(tile[j][i]);
  }
}

// ---------------------------------------------------------------- LN->q->u/su/cb tail (k0 only)
__device__ __forceinline__ void lnqu_tail_p(
    const float* Vs, float* Ys, float* Qs, float* Pp, float* SUb, float* CBb,
    const float* __restrict__ g_s, const float* __restrict__ b_s,
    const unsigned short* __restrict__ Wq_t, const unsigned short* __restrict__ Wk_b,
    const float* __restrict__ g_f, const float* __restrict__ b_f,
    unsigned short* __restrict__ u_buf, float* __restrict__ su_buf, float* __restrict__ cb_buf,
    int b, int k0, int tid)
{
  const int w = tid >> 6, L = tid & 63;
  {
    const float v0 = Vs[w*256+L], v1 = Vs[w*256+64+L], v2 = Vs[w*256+128+L], v3 = Vs[w*256+192+L];
    float s = v0+v1+v2+v3;
    #pragma unroll
    for (int m = 1; m < 64; m <<= 1) s += __shfl_xor(s, m);
    const float mean = s * (1.f/DD);
    const float d0 = v0-mean, d1 = v1-mean, d2 = v2-mean, d3 = v3-mean;
    float s2 = d0*d0 + d1*d1 + d2*d2 + d3*d3;
    #pragma unroll
    for (int m = 1; m < 64; m <<= 1) s2 += __shfl_xor(s2, m);
    const float rs = rsqrtf(s2 * (1.f/DD) + LN_EPS);
    Ys[L*4+w]       = d0*rs*g_s[L]      + b_s[L];
    Ys[(64+L)*4+w]  = d1*rs*g_s[64+L]   + b_s[64+L];
    Ys[(128+L)*4+w] = d2*rs*g_s[128+L]  + b_s[128+L];
    Ys[(192+L)*4+w] = d3*rs*g_s[192+L]  + b_s[192+L];
  }
  __syncthreads();
  {
    float acc[4][4] = {};
    for (int cc = w*64; cc < w*64+64; ++cc) {
      const float4v xv = *reinterpret_cast<const float4v*>(Ys + cc*4);
      const uint2v wr = *reinterpret_cast<const uint2v*>(Wq_t + (size_t)cc*DD + 4*L);
      const float w0 = bflo(wr[0]), w1 = bfhi(wr[0]), w2 = bflo(wr[1]), w3 = bfhi(wr[1]);
      #pragma unroll
      for (int s = 0; s < 4; ++s) {
        acc[s][0] += xv[s]*w0; acc[s][1] += xv[s]*w1;
        acc[s][2] += xv[s]*w2; acc[s][3] += xv[s]*w3;
      }
    }
    #pragma unroll
    for (int s = 0; s < 4; ++s)
      *reinterpret_cast<float4v*>(Pp + (w*4+s)*256 + 4*L) = *reinterpret_cast<const float4v*>(acc[s]);
  }
  __syncthreads();
  for (int i = tid; i < 4*DD; i += 256) {
    const int kk = i >> 8, d = i & 255;
    Qs[d*4+kk] = Pp[(0*4+kk)*256+d] + Pp[(1*4+kk)*256+d] + Pp[(2*4+kk)*256+d] + Pp[(3*4+kk)*256+d];
  }
  __syncthreads();
  {
    float acc[4][4] = {};
    for (int d = w*64; d < w*64+64; ++d) {
      const float4v xv = *reinterpret_cast<const float4v*>(Qs + d*4);
      const uint2v wr = *reinterpret_cast<const uint2v*>(Wk_b + (size_t)d*DD + 4*L);
      const float w0 = bflo(wr[0]), w1 = bfhi(wr[0]), w2 = bflo(wr[1]), w3 = bfhi(wr[1]);
      #pragma unroll
      for (int s = 0; s < 4; ++s) {
        acc[s][0] += xv[s]*w0; acc[s][1] += xv[s]*w1;
        acc[s][2] += xv[s]*w2; acc[s][3] += xv[s]*w3;
      }
    }
    #pragma unroll
    for (int s = 0; s < 4; ++s)
      *reinterpret_cast<float4v*>(Pp + (w*4+s)*256 + 4*L) = *reinterpret_cast<const float4v*>(acc[s]);
  }
  __syncthreads();
  for (int i = tid; i < 4*DD; i += 256) {
    const int kk = i >> 8, cc = i & 255;
    const float qk = Pp[(0*4+kk)*256+cc] + Pp[(1*4+kk)*256+cc] + Pp[(2*4+kk)*256+cc] + Pp[(3*4+kk)*256+cc];
    const float uv = qk * g_f[cc];
    u_buf[(size_t)(b*KS + k0 + kk)*DD + cc] = f2bf(uv);
    SUb[kk*256+cc] = uv;
    CBb[kk*256+cc] = qk * b_f[cc];
  }
  __syncthreads();
  {
    float s  = SUb[w*256+L] + SUb[w*256+64+L] + SUb[w*256+128+L] + SUb[w*256+192+L];
    float cv = CBb[w*256+L] + CBb[w*256+64+L] + CBb[w*256+128+L] + CBb[w*256+192+L];
    #pragma unroll
    for (int m = 1; m < 64; m <<= 1) { s += __shfl_xor(s, m); cv += __shfl_xor(cv, m); }
    if (L == 0) { su_buf[b*KS + k0 + w] = s; cb_buf[b*KS + k0 + w] = cv; }
  }
}

// ---------------------------------------------------------------- K0 (initial u only)
__global__ void k0_kernel(const float* __restrict__ slots_init,
                          const float* __restrict__ g_s, const float* __restrict__ b_s,
                          const unsigned short* __restrict__ Wq_t, const unsigned short* __restrict__ Wk_b,
                          const float* __restrict__ g_f, const float* __restrict__ b_f,
                          unsigned short* __restrict__ u_buf, float* __restrict__ su_buf,
                          float* __restrict__ cb_buf)
{
  const int b = blockIdx.x >> 2, k0 = (blockIdx.x & 3) * 4;
  const int tid = threadIdx.x;
  __shared__ __align__(16) float Vs[4*DD];
  __shared__ __align__(16) float Ys[DD*4];
  __shared__ __align__(16) float Qs[DD*4];
  __shared__ __align__(16) float Pp[4*4*DD];
  __shared__ __align__(16) float SUb[4*DD];
  __shared__ __align__(16) float CBb[4*DD];
  for (int i = tid; i < 4*DD; i += 256)
    Vs[i] = slots_init[(size_t)(b*KS + k0)*DD + i];
  __syncthreads();
  lnqu_tail_p(Vs, Ys, Qs, Pp, SUb, CBb, g_s, b_s, Wq_t, Wk_b, g_f, b_f,
              u_buf, su_buf, cb_buf, b, k0, tid);
}

// ---------------------------------------------------------------- phase A (r8 + pipeline + split acc)
template<int MODE, int LAST>
__launch_bounds__(256, 2)
__global__ void phaseA_kernel(const float* __restrict__ feat,
                              unsigned short* __restrict__ xb, float* __restrict__ stats,
                              const unsigned short* __restrict__ u_buf,
                              const float* __restrict__ su_buf,
                              const float* __restrict__ cb_buf,
                              float* __restrict__ P_part,
                              float* __restrict__ S_part,
                              float* __restrict__ R_part,
                              float* __restrict__ attn_out)
{
  __shared__ __align__(16) unsigned int xl[4][128*36];
  __shared__ float ssh[4][16];
  __shared__ float rsh[4][16];

  const int b   = blockIdx.x / NBLK;
  const int blk = blockIdx.x - b*NBLK;
  const int tid = threadIdx.x;
  const int w = tid >> 6;
  const int l = tid & 63;
  const int c = l & 15;
  const int g = l >> 4;

  bf16x8 ufrag[8];
  {
    const bf16x8* up = reinterpret_cast<const bf16x8*>(u_buf + (size_t)(b*KS + c)*DD);
    #pragma unroll
    for (int kk = 0; kk < 8; ++kk) ufrag[kk] = up[4*kk + g];
  }
  const float su_c = su_buf[b*KS + c];
  const float cb_c = cb_buf[b*KS + c];

  float4v Pacc[16];
  #pragma unroll
  for (int t = 0; t < 16; ++t) Pacc[t] = (float4v){0.f,0.f,0.f,0.f};
  float S_acc = 0.f, R_acc = 0.f;

  unsigned int* myxl = xl[w];
  const int rbase = 8*(c>>2) + (c&3);   // n_local = rbase + 4*tp

  // shared per-pass tail: softmax over slots + P-step MFMAs (r8-verbatim logic)
  auto tailpass = [&](int n0, const float4v* Ct, const float* m_t, const float* rs_t) {
    float arr[8];
    #pragma unroll
    for (int tp = 0; tp < 2; ++tp) {
      float lv[4], rsr[4], mr[4];
      #pragma unroll
      for (int r = 0; r < 4; ++r) {
        const int src = 4*g + r;
        rsr[r] = __shfl(rs_t[tp], src);
        mr[r]  = __shfl(m_t[tp],  src);
        lv[r]  = 0.0625f * (rsr[r]*(Ct[tp][r] - mr[r]*su_c) + cb_c);
      }
      float a_[4];
      #pragma unroll
      for (int r = 0; r < 4; ++r) {
        float v = lv[r];
        v = fmaxf(v, __shfl_xor(v,1));
        v = fmaxf(v, __shfl_xor(v,2));
        v = fmaxf(v, __shfl_xor(v,4));
        v = fmaxf(v, __shfl_xor(v,8));
        const float e = __expf(lv[r] - v);
        float s = e;
        s += __shfl_xor(s,1);
        s += __shfl_xor(s,2);
        s += __shfl_xor(s,4);
        s += __shfl_xor(s,8);
        const float a = e / s;
        a_[r] = a;
        S_acc += a;
        R_acc += a * rsr[r] * mr[r];
        arr[4*tp + r] = a * rsr[r];
      }
      if (LAST) {
        float4v av = {a_[0], a_[1], a_[2], a_[3]};
        *reinterpret_cast<float4v*>(attn_out + (size_t)(b*KS + c)*NTOK + (size_t)(n0 + 8*g + 4*tp)) = av;
      }
    }
    bf16x8 afrag;
    #pragma unroll
    for (int j = 0; j < 8; ++j) afrag[j] = (__bf16)arr[j];

    #pragma unroll
    for (int t = 0; t < 16; ++t) {
      const unsigned int* rp = &myxl[(t*8 + (c>>1))*36 + 8*g];
      const uint4v q0 = *reinterpret_cast<const uint4v*>(rp);
      const uint4v q1 = *reinterpret_cast<const uint4v*>(rp + 4);
      const unsigned int sel = (c & 1) ? 0x07060302u : 0x05040100u;
      uint4v bd;
      bd[0] = __builtin_amdgcn_perm(q0[1], q0[0], sel);
      bd[1] = __builtin_amdgcn_perm(q0[3], q0[2], sel);
      bd[2] = __builtin_amdgcn_perm(q1[1], q1[0], sel);
      bd[3] = __builtin_amdgcn_perm(q1[3], q1[2], sel);
      const bf16x8 bfrag = __builtin_bit_cast(bf16x8, bd);
      Pacc[t] = __builtin_amdgcn_mfma_f32_16x16x32_bf16(afrag, bfrag, Pacc[t], 0, 0, 0);
    }
  };

  if constexpr (MODE == 1) {
    // register-double-buffered pipeline: next pass's loads issue before current compute
    auto ldp = [&](int pass, bf16x8* r0, bf16x8* r1, float2& s0, float2& s1) {
      const int n0 = blk*(NTOK/NBLK) + pass*128 + w*32;
      const size_t row0 = (size_t)b*NTOK + (size_t)(n0 + rbase);
      const bf16x8* p0v = reinterpret_cast<const bf16x8*>(xb + row0*FEATN);
      const bf16x8* p1v = reinterpret_cast<const bf16x8*>(xb + (row0 + 4)*FEATN);
      #pragma unroll
      for (int kk = 0; kk < 8; ++kk) { r0[kk] = p0v[4*kk + g]; r1[kk] = p1v[4*kk + g]; }
      s0 = *reinterpret_cast<const float2*>(stats + row0*2);
      s1 = *reinterpret_cast<const float2*>(stats + (row0 + 4)*2);
    };
    auto dop = [&](int pass, const bf16x8* xr0, const bf16x8* xr1, float2 st0, float2 st1) {
      const int n0 = blk*(NTOK/NBLK) + pass*128 + w*32;
      float4v Ct[2]; float m_t[2], rs_t[2];
      #pragma unroll
      for (int tp = 0; tp < 2; ++tp) {
        const int nloc = rbase + 4*tp;
        float4v Ca = (float4v){0.f,0.f,0.f,0.f}, Cb = Ca;
        #pragma unroll
        for (int kk = 0; kk < 8; ++kk) {
          const bf16x8 af = tp ? xr1[kk] : xr0[kk];
          const uint4v ad = __builtin_bit_cast(uint4v, af);
          const int pb = (16*kk + 4*g)*36 + nloc;
          myxl[pb      ] = ad[0];
          myxl[pb + 36 ] = ad[1];
          myxl[pb + 72 ] = ad[2];
          myxl[pb + 108] = ad[3];
          if (kk & 1) Cb = __builtin_amdgcn_mfma_f32_16x16x32_bf16(af, ufrag[kk], Cb, 0, 0, 0);
          else        Ca = __builtin_amdgcn_mfma_f32_16x16x32_bf16(af, ufrag[kk], Ca, 0, 0, 0);
        }
        Ct[tp] = Ca + Cb;
        m_t[tp]  = tp ? st1.x : st0.x;
        rs_t[tp] = tp ? st1.y : st0.y;
      }
      tailpass(n0, Ct, m_t, rs_t);
    };

    bf16x8 A0[8], A1[8], B0[8], B1[8];
    float2 sa0, sa1, sb0, sb1;
    ldp(0, A0, A1, sa0, sa1);
    ldp(1, B0, B1, sb0, sb1);
    dop(0, A0, A1, sa0, sa1);
    ldp(2, A0, A1, sa0, sa1);
    dop(1, B0, B1, sb0, sb1);
    ldp(3, B0, B1, sb0, sb1);
    dop(2, A0, A1, sa0, sa1);
    dop(3, B0, B1, sb0, sb1);
  } else {
    for (int pass = 0; pass < 4; ++pass) {
      const int n0 = blk*(NTOK/NBLK) + pass*128 + w*32;
      float4v Ct[2];
      float m_t[2], rs_t[2];
      #pragma unroll
      for (int tp = 0; tp < 2; ++tp) {
        const int nloc = rbase + 4*tp;
        const size_t row = (size_t)b*NTOK + (size_t)(n0 + nloc);
        const float* fr = feat + row*FEATN;
        float4v xf[16];
        #pragma unroll
        for (int kk = 0; kk < 8; ++kk) {
          xf[2*kk]   = *reinterpret_cast<const float4v*>(fr + 32*kk + 8*g);
          xf[2*kk+1] = *reinterpret_cast<const float4v*>(fr + 32*kk + 8*g + 4);
        }
        unsigned short* xw = xb + row*FEATN;
        float sum = 0.f, sq = 0.f;
        float4v Ca = (float4v){0.f,0.f,0.f,0.f}, Cb = Ca;
        #pragma unroll
        for (int kk = 0; kk < 8; ++kk) {
          const float4v x0 = xf[2*kk], x1 = xf[2*kk+1];
          sum += x0[0]+x0[1]+x0[2]+x0[3] + x1[0]+x1[1]+x1[2]+x1[3];
          sq  += x0[0]*x0[0]+x0[1]*x0[1]+x0[2]*x0[2]+x0[3]*x0[3]
               + x1[0]*x1[0]+x1[1]*x1[1]+x1[2]*x1[2]+x1[3]*x1[3];
          bf16x8 af;
          af[0]=(__bf16)x0[0]; af[1]=(__bf16)x0[1]; af[2]=(__bf16)x0[2]; af[3]=(__bf16)x0[3];
          af[4]=(__bf16)x1[0]; af[5]=(__bf16)x1[1]; af[6]=(__bf16)x1[2]; af[7]=(__bf16)x1[3];
          *reinterpret_cast<bf16x8*>(xw + 32*kk + 8*g) = af;
          const uint4v ad = __builtin_bit_cast(uint4v, af);
          const int pb = (16*kk + 4*g)*36 + nloc;
          myxl[pb      ] = ad[0];
          myxl[pb + 36 ] = ad[1];
          myxl[pb + 72 ] = ad[2];
          myxl[pb + 108] = ad[3];
          if (kk & 1) Cb = __builtin_amdgcn_mfma_f32_16x16x32_bf16(af, ufrag[kk], Cb, 0, 0, 0);
          else        Ca = __builtin_amdgcn_mfma_f32_16x16x32_bf16(af, ufrag[kk], Ca, 0, 0, 0);
        }
        sum += __shfl_xor(sum,16); sum += __shfl_xor(sum,32);
        sq  += __shfl_xor(sq ,16); sq  += __shfl_xor(sq ,32);
        const float mean = sum * (1.f/FEATN);
        const float var  = sq  * (1.f/FEATN) - mean*mean;
        m_t[tp]  = mean;
        rs_t[tp] = rsqrtf(var + LN_EPS);
        float2 st; st.x = m_t[tp]; st.y = rs_t[tp];
        *reinterpret_cast<float2*>(stats + row*2) = st;
        Ct[tp] = Ca + Cb;
      }
      tailpass(n0, Ct, m_t, rs_t);
    }
  }

  S_acc += __shfl_xor(S_acc,16); S_acc += __shfl_xor(S_acc,32);
  R_acc += __shfl_xor(R_acc,16); R_acc += __shfl_xor(R_acc,32);
  if (g == 0) { ssh[w][c] = S_acc; rsh[w][c] = R_acc; }

  float* pf = reinterpret_cast<float*>(myxl);
  #pragma unroll
  for (int t = 0; t < 16; ++t) {
    #pragma unroll
    for (int r = 0; r < 4; ++r) pf[(4*g + r)*256 + t*16 + c] = Pacc[t][r];
  }
  __syncthreads();
  {
    float* outp = P_part + (size_t)blockIdx.x * (KS*DD);
    const float* p0 = reinterpret_cast<const float*>(&xl[0][0]);
    const float* p1 = p0 + 4608;
    const float* p2 = p0 + 9216;
    const float* p3 = p0 + 13824;
    for (int i = tid; i < KS*DD; i += 256) outp[i] = p0[i]+p1[i]+p2[i]+p3[i];
    if (tid < KS) {
      S_part[blockIdx.x*KS + tid] = ssh[0][tid]+ssh[1][tid]+ssh[2][tid]+ssh[3][tid];
      R_part[blockIdx.x*KS + tid] = rsh[0][tid]+rsh[1][tid]+rsh[2][tid]+rsh[3][tid];
    }
  }
}

// ---------------------------------------------------------------- fused slot update + next-iter tail
// grid = BB*KS = 256 blocks, 256 threads, one slot each. Arena non-overlapping. (r8-verbatim)
template<int LAST, int NEXT>
__global__ void fusedB_kernel(const float* __restrict__ P_part, const float* __restrict__ S_part,
                              const float* __restrict__ R_part, const float* __restrict__ slots_in,
                              const float* __restrict__ g_f, const float* __restrict__ b_f,
                              const unsigned short* __restrict__ Wv_t,
                              const unsigned short* __restrict__ wih_t,
                              const unsigned short* __restrict__ whh_t,
                              const float* __restrict__ b_ih, const float* __restrict__ b_hh,
                              const float* __restrict__ g_m, const float* __restrict__ b_m,
                              const unsigned short* __restrict__ W1_t, const float* __restrict__ b1,
                              const unsigned short* __restrict__ W2_t, const float* __restrict__ b2v,
                              const float* __restrict__ g_s, const float* __restrict__ b_s,
                              const unsigned short* __restrict__ Wq_t,
                              const unsigned short* __restrict__ Wk_b,
                              float* __restrict__ slots_next, float* __restrict__ out_slots,
                              unsigned short* __restrict__ u_buf, float* __restrict__ su_buf,
                              float* __restrict__ cb_buf)
{
  const int b = blockIdx.x >> 4, k = blockIdx.x & 15;
  const int tid = threadIdx.x;
  const int w = tid >> 6, L = tid & 63;

  __shared__ __align__(16) float arena[9984];
  __shared__ float SRsh[2];
  __shared__ float redsh[8];

  float* Pp    = arena;
  float* Hsh   = arena + 6144;
  float* Tsh   = arena + 6400;
  float* Ush   = arena + 6656;
  float* Gish  = arena + 6912;
  float* Ghsh  = arena + 7680;
  float* Hpsh  = arena + 8448;
  float* Ysh   = arena + 8704;
  float* Hidsh = arena + 8960;

  Hsh[tid] = slots_in[(size_t)(b*KS + k)*DD + tid];
  if (tid < 64) {
    const int p = tid & 31;
    const float* sp = (tid < 32) ? S_part : R_part;
    float v = sp[(b*NBLK + p)*KS + k];
    v += __shfl_xor(v, 1); v += __shfl_xor(v, 2); v += __shfl_xor(v, 4);
    v += __shfl_xor(v, 8); v += __shfl_xor(v, 16);
    if (p == 0) SRsh[tid >> 5] = v;
  }
  __syncthreads();

  {
    const float S = SRsh[0], R = SRsh[1];
    const float inv = 1.f / (S + 1.f);
    const float* pb = P_part + (size_t)(b*NBLK)*KS*DD + (size_t)k*DD + tid;
    float p0 = 0.f, p1 = 0.f, p2 = 0.f, p3 = 0.f;
    #pragma unroll 2
    for (int p = 0; p < NBLK; p += 4) {
      p0 += pb[(size_t)(p+0)*KS*DD];
      p1 += pb[(size_t)(p+1)*KS*DD];
      p2 += pb[(size_t)(p+2)*KS*DD];
      p3 += pb[(size_t)(p+3)*KS*DD];
    }
    const float P = (p0 + p1) + (p2 + p3);
    Tsh[tid] = (g_f[tid]*(P - R) + S*b_f[tid]) * inv;
  }
  __syncthreads();

  {
    const int c0 = 4*L;
    float a0 = 0.f, a1 = 0.f, a2 = 0.f, a3 = 0.f;
    for (int cc = w*64; cc < w*64+64; ++cc) {
      const float x = Tsh[cc];
      const uint2v wr = *reinterpret_cast<const uint2v*>(Wv_t + (size_t)cc*DD + c0);
      a0 += x*bflo(wr[0]); a1 += x*bfhi(wr[0]);
      a2 += x*bflo(wr[1]); a3 += x*bfhi(wr[1]);
    }
    float4v av = {a0, a1, a2, a3};
    *reinterpret_cast<float4v*>(Pp + w*256 + c0) = av;
  }
  __syncthreads();
  Ush[tid] = Pp[tid] + Pp[256+tid] + Pp[512+tid] + Pp[768+tid];
  __syncthreads();

  {
    const int c0 = 4*L;
    float ai[3][4] = {}, ah[3][4] = {};
    for (int cc = w*64; cc < w*64+64; ++cc) {
      const float xi = Ush[cc], xh = Hsh[cc];
      #pragma unroll
      for (int c = 0; c < 3; ++c) {
        const uint2v wi = *reinterpret_cast<const uint2v*>(wih_t + (size_t)cc*768 + c0 + 256*c);
        const uint2v wh = *reinterpret_cast<const uint2v*>(whh_t + (size_t)cc*768 + c0 + 256*c);
        ai[c][0] += xi*bflo(wi[0]); ai[c][1] += xi*bfhi(wi[0]);
        ai[c][2] += xi*bflo(wi[1]); ai[c][3] += xi*bfhi(wi[1]);
        ah[c][0] += xh*bflo(wh[0]); ah[c][1] += xh*bfhi(wh[0]);
        ah[c][2] += xh*bflo(wh[1]); ah[c][3] += xh*bfhi(wh[1]);
      }
    }
    #pragma unroll
    for (int c = 0; c < 3; ++c) {
      *reinterpret_cast<float4v*>(Pp + w*768 + 256*c + c0)        = *reinterpret_cast<const float4v*>(ai[c]);
      *reinterpret_cast<float4v*>(Pp + 3072 + w*768 + 256*c + c0) = *reinterpret_cast<const float4v*>(ah[c]);
    }
  }
  __syncthreads();
  for (int j = tid; j < 768; j += 256) {
    Gish[j] = b_ih[j] + Pp[j] + Pp[768+j] + Pp[1536+j] + Pp[2304+j];
    Ghsh[j] = b_hh[j] + Pp[3072+j] + Pp[3840+j] + Pp[4608+j] + Pp[5376+j];
  }
  __syncthreads();

  {
    const int d = tid;
    const float r = sigm(Gish[d] + Ghsh[d]);
    const float z = sigm(Gish[256+d] + Ghsh[256+d]);
    const float n = tanhf(Gish[512+d] + r*Ghsh[512+d]);
    const float hp = (1.f - z)*n + z*Hsh[d];
    Hpsh[d] = hp;
    float s = hp;
    #pragma unroll
    for (int m = 1; m < 64; m <<= 1) s += __shfl_xor(s, m);
    if (L == 0) redsh[w] = s;
    __syncthreads();
    const float mean = (redsh[0]+redsh[1]+redsh[2]+redsh[3]) * (1.f/DD);
    const float dv = hp - mean;
    float s2 = dv*dv;
    #pragma unroll
    for (int m = 1; m < 64; m <<= 1) s2 += __shfl_xor(s2, m);
    if (L == 0) redsh[4+w] = s2;
    __syncthreads();
    const float var = (redsh[4]+redsh[5]+redsh[6]+redsh[7]) * (1.f/DD);
    Ysh[d] = dv * rsqrtf(var + LN_EPS) * g_m[d] + b_m[d];
  }
  __syncthreads();

  {
    const int c0 = 4*L;
    float a[4][4] = {};
    for (int cc = w*64; cc < w*64+64; ++cc) {
      const float x = Ysh[cc];
      #pragma unroll
      for (int c = 0; c < 4; ++c) {
        const uint2v wr = *reinterpret_cast<const uint2v*>(W1_t + (size_t)cc*1024 + c0 + 256*c);
        a[c][0] += x*bflo(wr[0]); a[c][1] += x*bfhi(wr[0]);
        a[c][2] += x*bflo(wr[1]); a[c][3] += x*bfhi(wr[1]);
      }
    }
    #pragma unroll
    for (int c = 0; c < 4; ++c)
      *reinterpret_cast<float4v*>(Pp + w*1024 + 256*c + c0) = *reinterpret_cast<const float4v*>(a[c]);
  }
  __syncthreads();
  for (int j = tid; j < 1024; j += 256)
    Hidsh[j] = fmaxf(b1[j] + Pp[j] + Pp[1024+j] + Pp[2048+j] + Pp[3072+j], 0.f);
  __syncthreads();

  {
    const int c0 = 4*L;
    float a0 = 0.f, a1 = 0.f, a2 = 0.f, a3 = 0.f;
    for (int cc = w*256; cc < w*256+256; ++cc) {
      const float x = Hidsh[cc];
      const uint2v wr = *reinterpret_cast<const uint2v*>(W2_t + (size_t)cc*DD + c0);
      a0 += x*bflo(wr[0]); a1 += x*bfhi(wr[0]);
      a2 += x*bflo(wr[1]); a3 += x*bfhi(wr[1]);
    }
    float4v av = {a0, a1, a2, a3};
    *reinterpret_cast<float4v*>(Pp + w*256 + c0) = av;
  }
  __syncthreads();
  {
    const int d = tid;
    const float v = b2v[d] + Pp[d] + Pp[256+d] + Pp[512+d] + Pp[768+d] + Hpsh[d];
    Tsh[d] = v;
    slots_next[(size_t)(b*KS + k)*DD + d] = v;
    if (LAST) out_slots[(size_t)(b*KS + k)*DD + d] = v;
  }

  if constexpr (NEXT) {
    __syncthreads();
    {
      const float v = Tsh[tid];
      float s = v;
      #pragma unroll
      for (int m = 1; m < 64; m <<= 1) s += __shfl_xor(s, m);
      if (L == 0) redsh[w] = s;
      __syncthreads();
      const float mean = (redsh[0]+redsh[1]+redsh[2]+redsh[3]) * (1.f/DD);
      const float dv = v - mean;
      float s2 = dv*dv;
      #pragma unroll
      for (int m = 1; m < 64; m <<= 1) s2 += __shfl_xor(s2, m);
      if (L == 0) redsh[4+w] = s2;
      __syncthreads();
      const float var = (redsh[4]+redsh[5]+redsh[6]+redsh[7]) * (1.f/DD);
      Ush[tid] = dv * rsqrtf(var + LN_EPS) * g_s[tid] + b_s[tid];
    }
    __syncthreads();
    {
      const int c0 = 4*L;
      float a0 = 0.f, a1 = 0.f, a2 = 0.f, a3 = 0.f;
      for (int cc = w*64; cc < w*64+64; ++cc) {
        const float x = Ush[cc];
        const uint2v wr = *reinterpret_cast<const uint2v*>(Wq_t + (size_t)cc*DD + c0);
        a0 += x*bflo(wr[0]); a1 += x*bfhi(wr[0]);
        a2 += x*bflo(wr[1]); a3 += x*bfhi(wr[1]);
      }
      float4v av = {a0, a1, a2, a3};
      *reinterpret_cast<float4v*>(Pp + w*256 + c0) = av;
    }
    __syncthreads();
    Hsh[tid] = Pp[tid] + Pp[256+tid] + Pp[512+tid] + Pp[768+tid];
    __syncthreads();
    {
      const int c0 = 4*L;
      float a0 = 0.f, a1 = 0.f, a2 = 0.f, a3 = 0.f;
      for (int dd = w*64; dd < w*64+64; ++dd) {
        const float x = Hsh[dd];
        const uint2v wr = *reinterpret_cast<const uint2v*>(Wk_b + (size_t)dd*DD + c0);
        a0 += x*bflo(wr[0]); a1 += x*bfhi(wr[0]);
        a2 += x*bflo(wr[1]); a3 += x*bfhi(wr[1]);
      }
      float4v av = {a0, a1, a2, a3};
      *reinterpret_cast<float4v*>(Pp + w*256 + c0) = av;
    }
    __syncthreads();
    {
      const int cidx = tid;
      const float qk = Pp[cidx] + Pp[256+cidx] + Pp[512+cidx] + Pp[768+cidx];
      const float uv = qk * g_f[cidx];
      u_buf[(size_t)(b*KS + k)*DD + cidx] = f2bf(uv);
      float s  = uv;
      float cv = qk * b_f[cidx];
      #pragma unroll
      for (int m = 1; m < 64; m <<= 1) { s += __shfl_xor(s, m); cv += __shfl_xor(cv, m); }
      if (L == 0) { redsh[w] = s; redsh[4+w] = cv; }
      __syncthreads();
      if (tid == 0) {
        su_buf[b*KS + k] = redsh[0]+redsh[1]+redsh[2]+redsh[3];
        cb_buf[b*KS + k] = redsh[4]+redsh[5]+redsh[6]+redsh[7];
      }
    }
  }
}

// ---------------------------------------------------------------- host
extern "C" void kernel_launch(void* const* d_in, const int* in_sizes, int n_in,
                              void* d_out, int out_size, void* d_ws, size_t ws_size,
                              hipStream_t stream)
{
  const float* features   = (const float*)d_in[0];
  const float* slots_init = (const float*)d_in[1];
  const float* g_f = (const float*)d_in[2];
  const float* b_f = (const float*)d_in[3];
  const float* g_s = (const float*)d_in[4];
  const float* b_s = (const float*)d_in[5];
  const float* g_m = (const float*)d_in[6];
  const float* b_m = (const float*)d_in[7];
  const float* Wq  = (const float*)d_in[8];
  const float* Wk  = (const float*)d_in[9];
  const float* Wv  = (const float*)d_in[10];
  const float* w_ih = (const float*)d_in[11];
  const float* w_hh = (const float*)d_in[12];
  const float* b_ih = (const float*)d_in[13];
  const float* b_hh = (const float*)d_in[14];
  const float* W1  = (const float*)d_in[15];
  const float* b1  = (const float*)d_in[16];
  const float* W2  = (const float*)d_in[17];
  const float* b2  = (const float*)d_in[18];

  float* out_slots = (float*)d_out;
  float* out_attn  = out_slots + (size_t)BB*KS*DD;

  char* ws = (char*)d_ws;
  size_t off = 0;
  auto alloc = [&](size_t bytes) -> void* {
    void* p = ws + off;
    off += (bytes + 255) & ~(size_t)255;
    return p;
  };
  unsigned short* u_buf  = (unsigned short*)alloc((size_t)BB*KS*DD*2);
  float*          su_buf = (float*)alloc((size_t)BB*KS*4);
  float*          cb_buf = (float*)alloc((size_t)BB*KS*4);
  float*          P_part = (float*)alloc((size_t)BB*NBLK*KS*DD*4);
  float*          S_part = (float*)alloc((size_t)BB*NBLK*KS*4);
  float*          R_part = (float*)alloc((size_t)BB*NBLK*KS*4);
  float*          slots_ws = (float*)alloc((size_t)BB*KS*DD*4);
  unsigned short* Wv_t  = (unsigned short*)alloc((size_t)256*256*2);
  unsigned short* wih_t = (unsigned short*)alloc((size_t)256*768*2);
  unsigned short* whh_t = (unsigned short*)alloc((size_t)256*768*2);
  unsigned short* W1_t  = (unsigned short*)alloc((size_t)256*1024*2);
  unsigned short* W2_t  = (unsigned short*)alloc((size_t)1024*256*2);
  unsigned short* Wq_t  = (unsigned short*)alloc((size_t)256*256*2);
  unsigned short* Wk_b  = (unsigned short*)alloc((size_t)256*256*2);
  float*          stats = (float*)alloc((size_t)BB*NTOK*2*4);
  unsigned short* xb    = (unsigned short*)alloc((size_t)BB*NTOK*FEATN*2);
  (void)in_sizes; (void)n_in; (void)out_size; (void)ws_size;

  prep_w_kernel<<<272, 256, 0, stream>>>(Wv, w_ih, w_hh, W1, W2, Wq, Wk,
                                         Wv_t, wih_t, whh_t, W1_t, W2_t, Wq_t, Wk_b);
  k0_kernel<<<BB*4, 256, 0, stream>>>(slots_init, g_s, b_s, Wq_t, Wk_b, g_f, b_f,
                                      u_buf, su_buf, cb_buf);

  // iter 0
  phaseA_kernel<0,0><<<BB*NBLK, 256, 0, stream>>>(features, xb, stats, u_buf, su_buf, cb_buf,
                                                  P_part, S_part, R_part, out_attn);
  fusedB_kernel<0,1><<<BB*KS, 256, 0, stream>>>(P_part, S_part, R_part, slots_init, g_f, b_f,
                                                Wv_t, wih_t, whh_t, b_ih, b_hh, g_m, b_m,
                                                W1_t, b1, W2_t, b2, g_s, b_s, Wq_t, Wk_b,
                                                slots_ws, out_slots, u_buf, su_buf, cb_buf);
  // iter 1
  phaseA_kernel<1,0><<<BB*NBLK, 256, 0, stream>>>(features, xb, stats, u_buf, su_buf, cb_buf,
                                                  P_part, S_part, R_part, out_attn);
  fusedB_kernel<0,1><<<BB*KS, 256, 0, stream>>>(P_part, S_part, R_part, slots_ws, g_f, b_f,
                                                Wv_t, wih_t, whh_t, b_ih, b_hh, g_m, b_m,
                                                W1_t, b1, W2_t, b2, g_s, b_s, Wq_t, Wk_b,
                                                slots_ws, out_slots, u_buf, su_buf, cb_buf);
  // iter 2
  phaseA_kernel<1,1><<<BB*NBLK, 256, 0, stream>>>(features, xb, stats, u_buf, su_buf, cb_buf,
                                                  P_part, S_part, R_part, out_attn);
  fusedB_kernel<1,0><<<BB*KS, 256, 0, stream>>>(P_part, S_part, R_part, slots_ws, g_f, b_f,
                                                Wv_t, wih_t, whh_t, b_ih, b_hh, g_m, b_m,
                                                W1_t, b1, W2_t, b2, g_s, b_s, Wq_t, Wk_b,
                                                slots_ws, out_slots, u_buf, su_buf, cb_buf);
}